// Round 1
// baseline (662.921 us; speedup 1.0000x reference)
//
#include <hip/hip_runtime.h>
#include <math.h>

#define N 512
#define CS 384
#define CZ 128
#define CH 16
#define NH 12
#define PQ 4
#define PV 8

// workspace layout (float offsets)
#define OFF_Q     0          // 512*192
#define OFF_K     98304      // 512*192
#define OFF_V     196608     // 512*192
#define OFF_QRAW  294912     // 512*144
#define OFF_KVRAW 368640     // 512*432
#define OFF_QPTS  589824     // 512*12*4*3
#define OFF_KPTS  663552     // 512*12*4*3
#define OFF_VPTS  737280     // 512*12*8*3
#define OFF_B     884736     // 512*512*12
#define OFF_CAT   4030464    // 512*2112
// end = 5111808 floats = 19.5 MiB

// ---------------- kernel 1: fused projections s @ {Wq, Wkv, Wqp, Wkvp} ----------------
__global__ __launch_bounds__(128) void proj_kernel(
    const float* __restrict__ s,
    const float* __restrict__ Wq,  const float* __restrict__ bq,
    const float* __restrict__ Wkv, const float* __restrict__ bkv,
    const float* __restrict__ Wqp, const float* __restrict__ bqp,
    const float* __restrict__ Wkvp,const float* __restrict__ bkvp,
    float* __restrict__ ws)
{
    __shared__ float srow[CS];
    const int n = blockIdx.x;
    for (int idx = threadIdx.x; idx < CS; idx += 128)
        srow[idx] = s[n * CS + idx];
    __syncthreads();

    const int u = blockIdx.y * 128 + threadIdx.x;  // 0..1151
    const float* W; float bias; int ncol, lc; int oidx;
    if (u < 192) {
        W = Wq; ncol = 192; lc = u; bias = bq[lc];
        oidx = OFF_Q + n * 192 + lc;                 // q[n][h*16+c]
    } else if (u < 576) {
        W = Wkv; ncol = 384; lc = u - 192; bias = bkv[lc];
        int h = lc >> 5, w = lc & 31;
        if (w < 16) oidx = OFF_K + n * 192 + h * 16 + w;
        else        oidx = OFF_V + n * 192 + h * 16 + (w - 16);
    } else if (u < 720) {
        W = Wqp; ncol = 144; lc = u - 576; bias = bqp[lc];
        oidx = OFF_QRAW + n * 144 + lc;
    } else {
        W = Wkvp; ncol = 432; lc = u - 720; bias = bkvp[lc];
        oidx = OFF_KVRAW + n * 432 + lc;
    }
    float acc = bias;
    for (int k = 0; k < CS; k++)
        acc += srow[k] * W[k * ncol + lc];
    ws[oidx] = acc;
}

// ---------------- kernel 2: rigid transform of point projections ----------------
__global__ __launch_bounds__(192) void point_kernel(
    const float* __restrict__ t_trans, const float* __restrict__ t_rots,
    float* __restrict__ ws)
{
    const int n = blockIdx.x;
    const int t = threadIdx.x;
    __shared__ float R[9], tr[3];
    if (t < 9) R[t] = t_rots[n * 9 + t];
    if (t < 3) tr[t] = t_trans[n * 3 + t];
    __syncthreads();

    float x0, x1, x2;
    int base;
    if (t < 48) {  // q points: idx = h*4+p
        int idx = t;
        x0 = ws[OFF_QRAW + n * 144 + 0 * 48 + idx];
        x1 = ws[OFF_QRAW + n * 144 + 1 * 48 + idx];
        x2 = ws[OFF_QRAW + n * 144 + 2 * 48 + idx];
        int h = idx >> 2, p = idx & 3;
        base = OFF_QPTS + ((n * NH + h) * PQ + p) * 3;
    } else {       // kv points: idx = h*12+p
        int idx = t - 48;
        x0 = ws[OFF_KVRAW + n * 432 + 0 * 144 + idx];
        x1 = ws[OFF_KVRAW + n * 432 + 1 * 144 + idx];
        x2 = ws[OFF_KVRAW + n * 432 + 2 * 144 + idx];
        int h = idx / 12, p = idx % 12;
        if (p < PQ) base = OFF_KPTS + ((n * NH + h) * PQ + p) * 3;
        else        base = OFF_VPTS + ((n * NH + h) * PV + (p - PQ)) * 3;
    }
    ws[base + 0] = R[0] * x0 + R[1] * x1 + R[2] * x2 + tr[0];
    ws[base + 1] = R[3] * x0 + R[4] * x1 + R[5] * x2 + tr[1];
    ws[base + 2] = R[6] * x0 + R[7] * x1 + R[8] * x2 + tr[2];
}

// ---------------- kernel 3: b = z @ Wb + bb ----------------
__global__ __launch_bounds__(256) void bz_kernel(
    const float* __restrict__ z, const float* __restrict__ Wb,
    const float* __restrict__ bb, float* __restrict__ ws)
{
    __shared__ float wb[CZ * NH];
    __shared__ float bbs[NH];
    __shared__ float zt[16][CZ];
    const int i = blockIdx.x;
    const int j0 = blockIdx.y * 16;
    const int t = threadIdx.x;

    for (int idx = t; idx < CZ * NH; idx += 256) wb[idx] = Wb[idx];
    if (t < NH) bbs[t] = bb[t];
    for (int idx = t; idx < 16 * CZ; idx += 256) {
        int jj = idx >> 7, c = idx & 127;
        zt[jj][c] = z[(size_t)(i * N + j0 + jj) * CZ + c];
    }
    __syncthreads();

    if (t < 192) {
        int jj = t / NH, h = t % NH;
        float acc = bbs[h];
        for (int c = 0; c < CZ; c++)
            acc += zt[jj][c] * wb[c * NH + h];
        ws[OFF_B + (size_t)(i * N + j0 + jj) * NH + h] = acc;
    }
}

// ---------------- kernel 4: attention core (block per query i) ----------------
__global__ __launch_bounds__(256) void attn_kernel(
    const float* __restrict__ z, const float* __restrict__ t_trans,
    const float* __restrict__ t_rots, const float* __restrict__ mask,
    const float* __restrict__ hweights, float* __restrict__ ws)
{
    const int i = blockIdx.x;
    const int t = threadIdx.x;
    __shared__ float a[NH][520];        // logits → probs (padded stride)
    __shared__ float qi[NH][CH];
    __shared__ float qpi[NH][PQ][3];
    __shared__ float hw[NH];
    __shared__ float Ri[9], ti[3];
    __shared__ float mi_s;
    __shared__ float zt[16][CZ];

    for (int idx = t; idx < 192; idx += 256) qi[idx >> 4][idx & 15] = ws[OFF_Q + i * 192 + idx];
    for (int idx = t; idx < 144; idx += 256) {
        int h = idx / 12, r = idx % 12;
        qpi[h][r / 3][r % 3] = ws[OFF_QPTS + i * 144 + idx];
    }
    if (t < NH) hw[t] = log1pf(expf(hweights[t])) * 0.13608276348795434f; // softplus * sqrt(1/54)
    if (t < 9) Ri[t] = t_rots[i * 9 + t];
    if (t < 3) ti[t] = t_trans[i * 3 + t];
    if (t == 0) mi_s = mask[i];
    __syncthreads();

    const float cqk = 0.14433756729740643f;  // sqrt(1/48)
    const float cb  = 0.5773502691896258f;   // sqrt(1/3)

    // phase 1: logits
    for (int j = t; j < N; j += 256) {
        float sm = 100000.0f * (mi_s * mask[j] - 1.0f);
        const float* krow  = ws + OFF_K    + j * 192;
        const float* kprow = ws + OFF_KPTS + j * 144;
        const float* brow  = ws + OFF_B + (size_t)(i * N + j) * NH;
        for (int h = 0; h < NH; h++) {
            float qk = 0.f;
            for (int c = 0; c < CH; c++) qk += qi[h][c] * krow[h * 16 + c];
            float d2 = 0.f;
            for (int p = 0; p < PQ; p++)
                for (int x = 0; x < 3; x++) {
                    float d = qpi[h][p][x] - kprow[h * 12 + p * 3 + x];
                    d2 += d * d;
                }
            a[h][j] = qk * cqk + cb * brow[h] - 0.5f * hw[h] * d2 + sm;
        }
    }
    __syncthreads();

    // phase 2: softmax per head row (wave w handles h = w, w+4, w+8)
    const int wave = t >> 6, lane = t & 63;
    for (int h = wave; h < NH; h += 4) {
        float m = -1e30f;
        for (int j = lane; j < N; j += 64) m = fmaxf(m, a[h][j]);
        for (int o = 32; o > 0; o >>= 1) m = fmaxf(m, __shfl_xor(m, o));
        float ssum = 0.f;
        for (int j = lane; j < N; j += 64) { float e = __expf(a[h][j] - m); a[h][j] = e; ssum += e; }
        for (int o = 32; o > 0; o >>= 1) ssum += __shfl_xor(ssum, o);
        float inv = 1.0f / ssum;
        for (int j = lane; j < N; j += 64) a[h][j] *= inv;
    }
    __syncthreads();

    float* cat = ws + OFF_CAT + (size_t)i * 2112;

    // phase 3: o = a @ v  (192 outputs)
    if (t < 192) {
        int h = t >> 4, c = t & 15;
        float acc = 0.f;
        for (int j = 0; j < N; j++)
            acc += a[h][j] * ws[OFF_V + j * 192 + h * 16 + c];
        cat[h * 16 + c] = acc;
    }
    // phase 4: o_pt = a @ v_pts, inverse transform, norm (96 outputs)
    if (t < 96) {
        int h = t >> 3, p = t & 7;
        float g0 = 0.f, g1 = 0.f, g2 = 0.f;
        for (int j = 0; j < N; j++) {
            float av = a[h][j];
            const float* vp = ws + OFF_VPTS + ((size_t)(j * NH + h) * PV + p) * 3;
            g0 += av * vp[0]; g1 += av * vp[1]; g2 += av * vp[2];
        }
        g0 -= ti[0]; g1 -= ti[1]; g2 -= ti[2];
        float l0 = Ri[0] * g0 + Ri[3] * g1 + Ri[6] * g2;
        float l1 = Ri[1] * g0 + Ri[4] * g1 + Ri[7] * g2;
        float l2 = Ri[2] * g0 + Ri[5] * g1 + Ri[8] * g2;
        float nrm = sqrtf(l0 * l0 + l1 * l1 + l2 * l2 + 1e-8f);
        int e = h * PV + p;
        cat[192 + e] = l0;
        cat[288 + e] = l1;
        cat[384 + e] = l2;
        cat[480 + e] = nrm;
    }

    // phase 5: o_pair = a @ z  (12*128 outputs, 6 per thread)
    float acc[6] = {0.f, 0.f, 0.f, 0.f, 0.f, 0.f};
    const int c = t & 127;
    const int h0 = t >> 7;  // 0 or 1
    for (int jt = 0; jt < N / 16; jt++) {
        __syncthreads();
        for (int idx = t; idx < 16 * CZ; idx += 256) {
            int jj = idx >> 7, cc = idx & 127;
            zt[jj][cc] = z[(size_t)(i * N + jt * 16 + jj) * CZ + cc];
        }
        __syncthreads();
        float zreg[16];
        for (int jj = 0; jj < 16; jj++) zreg[jj] = zt[jj][c];
        #pragma unroll
        for (int r = 0; r < 6; r++) {
            int h = h0 + 2 * r;
            float s6 = 0.f;
            for (int jj = 0; jj < 16; jj++)
                s6 += a[h][jt * 16 + jj] * zreg[jj];
            acc[r] += s6;
        }
    }
    #pragma unroll
    for (int r = 0; r < 6; r++) {
        int h = h0 + 2 * r;
        cat[576 + h * CZ + c] = acc[r];
    }
}

// ---------------- kernel 5: out = cat @ Wout + bout ----------------
__global__ __launch_bounds__(384) void out_kernel(
    const float* __restrict__ Wout, const float* __restrict__ bout,
    const float* __restrict__ ws, float* __restrict__ out)
{
    __shared__ float c0[2112], c1[2112];
    const int ib = blockIdx.x * 2;
    const int t = threadIdx.x;
    for (int idx = t; idx < 2112; idx += 384) {
        c0[idx] = ws[OFF_CAT + (size_t)ib * 2112 + idx];
        c1[idx] = ws[OFF_CAT + (size_t)(ib + 1) * 2112 + idx];
    }
    __syncthreads();
    float acc0 = 0.f, acc1 = 0.f;
    for (int k = 0; k < 2112; k++) {
        float w = Wout[(size_t)k * 384 + t];
        acc0 += c0[k] * w;
        acc1 += c1[k] * w;
    }
    out[(size_t)ib * 384 + t] = acc0 + bout[t];
    out[(size_t)(ib + 1) * 384 + t] = acc1 + bout[t];
}

extern "C" void kernel_launch(void* const* d_in, const int* in_sizes, int n_in,
                              void* d_out, int out_size, void* d_ws, size_t ws_size,
                              hipStream_t stream) {
    const float* s       = (const float*)d_in[0];
    const float* z       = (const float*)d_in[1];
    const float* t_trans = (const float*)d_in[2];
    const float* t_rots  = (const float*)d_in[3];
    const float* mask    = (const float*)d_in[4];
    const float* Wq      = (const float*)d_in[5];
    const float* bq      = (const float*)d_in[6];
    const float* Wkv     = (const float*)d_in[7];
    const float* bkv     = (const float*)d_in[8];
    const float* Wqp     = (const float*)d_in[9];
    const float* bqp     = (const float*)d_in[10];
    const float* Wkvp    = (const float*)d_in[11];
    const float* bkvp    = (const float*)d_in[12];
    const float* Wb      = (const float*)d_in[13];
    const float* bb      = (const float*)d_in[14];
    const float* hweights= (const float*)d_in[15];
    const float* Wout    = (const float*)d_in[16];
    const float* bout    = (const float*)d_in[17];
    float* ws  = (float*)d_ws;
    float* out = (float*)d_out;

    proj_kernel<<<dim3(N, 9), 128, 0, stream>>>(s, Wq, bq, Wkv, bkv, Wqp, bqp, Wkvp, bkvp, ws);
    point_kernel<<<N, 192, 0, stream>>>(t_trans, t_rots, ws);
    bz_kernel<<<dim3(N, N / 16), 256, 0, stream>>>(z, Wb, bb, ws);
    attn_kernel<<<N, 256, 0, stream>>>(z, t_trans, t_rots, mask, hweights, ws);
    out_kernel<<<N / 2, 384, 0, stream>>>(Wout, bout, ws, out);
}

// Round 2
// 489.893 us; speedup vs baseline: 1.3532x; 1.3532x over previous
//
#include <hip/hip_runtime.h>
#include <math.h>

#define N 512
#define CS 384
#define CZ 128
#define CH 16
#define NH 12
#define PQ 4
#define PV 8

// workspace layout (float offsets)
#define OFF_Q     0          // 512*192
#define OFF_K     98304      // 512*192
#define OFF_V     196608     // 512*192
#define OFF_QRAW  294912     // 512*144
#define OFF_KVRAW 368640     // 512*432
#define OFF_QPTS  589824     // 512*144
#define OFF_KPTS  663552     // 512*144
#define OFF_VPTS  737280     // 512*288
#define OFF_A     884736     // 512*12*512 = 3145728
#define OFF_CAT   4030464    // 512*2112
// end = 5111808 floats

// ---------------- kernel 1: fused projections, 16-row register tile ----------------
__global__ __launch_bounds__(128) void proj_kernel(
    const float* __restrict__ s,
    const float* __restrict__ Wq,  const float* __restrict__ bq,
    const float* __restrict__ Wkv, const float* __restrict__ bkv,
    const float* __restrict__ Wqp, const float* __restrict__ bqp,
    const float* __restrict__ Wkvp,const float* __restrict__ bkvp,
    float* __restrict__ ws)
{
    __shared__ float st[16 * CS];   // 24 KB
    const int n0 = blockIdx.x * 16;
    for (int idx = threadIdx.x * 4; idx < 16 * CS; idx += 128 * 4)
        *(float4*)&st[idx] = *(const float4*)&s[n0 * CS + idx];
    __syncthreads();

    const int tc = threadIdx.x & 31;   // col-quad id
    const int tr = threadIdx.x >> 5;   // row group 0..3
    const int u0 = blockIdx.y * 128 + tc * 4;  // all 4 cols in one segment (bounds 192/576/720 are 4-aligned)
    const int r0 = tr * 4;

    const float* W; const float* bptr; int ncol, lc0;
    if (u0 < 192)      { W = Wq;   bptr = bq;   ncol = 192; lc0 = u0; }
    else if (u0 < 576) { W = Wkv;  bptr = bkv;  ncol = 384; lc0 = u0 - 192; }
    else if (u0 < 720) { W = Wqp;  bptr = bqp;  ncol = 144; lc0 = u0 - 576; }
    else               { W = Wkvp; bptr = bkvp; ncol = 432; lc0 = u0 - 720; }

    float acc[4][4];
    #pragma unroll
    for (int r = 0; r < 4; r++)
        #pragma unroll
        for (int c = 0; c < 4; c++) acc[r][c] = 0.f;

    for (int k = 0; k < CS; k += 4) {
        float4 w0 = *(const float4*)&W[(k + 0) * ncol + lc0];
        float4 w1 = *(const float4*)&W[(k + 1) * ncol + lc0];
        float4 w2 = *(const float4*)&W[(k + 2) * ncol + lc0];
        float4 w3 = *(const float4*)&W[(k + 3) * ncol + lc0];
        #pragma unroll
        for (int r = 0; r < 4; r++) {
            float4 sv = *(const float4*)&st[(r0 + r) * CS + k];
            acc[r][0] += sv.x * w0.x + sv.y * w1.x + sv.z * w2.x + sv.w * w3.x;
            acc[r][1] += sv.x * w0.y + sv.y * w1.y + sv.z * w2.y + sv.w * w3.y;
            acc[r][2] += sv.x * w0.z + sv.y * w1.z + sv.z * w2.z + sv.w * w3.z;
            acc[r][3] += sv.x * w0.w + sv.y * w1.w + sv.z * w2.w + sv.w * w3.w;
        }
    }

    #pragma unroll
    for (int c = 0; c < 4; c++) {
        const int u = u0 + c;
        const float bias = bptr[lc0 + c];
        #pragma unroll
        for (int r = 0; r < 4; r++) {
            const int n = n0 + r0 + r;
            int oidx;
            if (u < 192) oidx = OFF_Q + n * 192 + u;
            else if (u < 576) {
                int lc = u - 192, h = lc >> 5, w = lc & 31;
                oidx = (w < 16) ? OFF_K + n * 192 + h * 16 + w
                                : OFF_V + n * 192 + h * 16 + (w - 16);
            } else if (u < 720) oidx = OFF_QRAW + n * 144 + (u - 576);
            else                oidx = OFF_KVRAW + n * 432 + (u - 720);
            ws[oidx] = acc[r][c] + bias;
        }
    }
}

// ---------------- kernel 2: rigid transform of point projections ----------------
__global__ __launch_bounds__(192) void point_kernel(
    const float* __restrict__ t_trans, const float* __restrict__ t_rots,
    float* __restrict__ ws)
{
    const int n = blockIdx.x;
    const int t = threadIdx.x;
    __shared__ float R[9], tr[3];
    if (t < 9) R[t] = t_rots[n * 9 + t];
    if (t < 3) tr[t] = t_trans[n * 3 + t];
    __syncthreads();

    float x0, x1, x2;
    int base;
    if (t < 48) {
        int idx = t;
        x0 = ws[OFF_QRAW + n * 144 + 0 * 48 + idx];
        x1 = ws[OFF_QRAW + n * 144 + 1 * 48 + idx];
        x2 = ws[OFF_QRAW + n * 144 + 2 * 48 + idx];
        int h = idx >> 2, p = idx & 3;
        base = OFF_QPTS + ((n * NH + h) * PQ + p) * 3;
    } else {
        int idx = t - 48;
        x0 = ws[OFF_KVRAW + n * 432 + 0 * 144 + idx];
        x1 = ws[OFF_KVRAW + n * 432 + 1 * 144 + idx];
        x2 = ws[OFF_KVRAW + n * 432 + 2 * 144 + idx];
        int h = idx / 12, p = idx % 12;
        if (p < PQ) base = OFF_KPTS + ((n * NH + h) * PQ + p) * 3;
        else        base = OFF_VPTS + ((n * NH + h) * PV + (p - PQ)) * 3;
    }
    ws[base + 0] = R[0] * x0 + R[1] * x1 + R[2] * x2 + tr[0];
    ws[base + 1] = R[3] * x0 + R[4] * x1 + R[5] * x2 + tr[1];
    ws[base + 2] = R[6] * x0 + R[7] * x1 + R[8] * x2 + tr[2];
}

// ---------------- kernel 3: logits fused with b = z@Wb (z read once) ----------------
__global__ __launch_bounds__(192) void logit_kernel(
    const float* __restrict__ z, const float* __restrict__ Wb,
    const float* __restrict__ bb, const float* __restrict__ mask,
    const float* __restrict__ hweights, float* __restrict__ ws)
{
    const int jt = blockIdx.x;   // 0..31 (16-j tile)
    const int i  = blockIdx.y;   // 0..511
    const int t  = threadIdx.x;  // 0..191

    __shared__ float zt[16 * 132];
    __shared__ float wbt[12 * 132];
    __shared__ float kt[16 * 200];
    __shared__ float kpt[16 * 148];
    __shared__ float qi[192];
    __shared__ float qpi[144];
    __shared__ float hws[NH], bbs[NH], mj[16];
    __shared__ float mi_s;

    {   // z tile 16x128, contiguous
        const float* src = z + ((size_t)i * N + jt * 16) * CZ;
        for (int idx = t * 4; idx < 2048; idx += 768) {
            float4 v = *(const float4*)&src[idx];
            int jj = idx >> 7, c = idx & 127;
            *(float4*)&zt[jj * 132 + c] = v;
        }
    }
    {   // k tile 16x192
        const float* src = ws + OFF_K + jt * 16 * 192;
        for (int idx = t * 4; idx < 3072; idx += 768) {
            float4 v = *(const float4*)&src[idx];
            int jj = idx / 192, c = idx % 192;
            *(float4*)&kt[jj * 200 + c] = v;
        }
    }
    {   // kpts tile 16x144
        const float* src = ws + OFF_KPTS + jt * 16 * 144;
        for (int idx = t * 4; idx < 2304; idx += 768) {
            float4 v = *(const float4*)&src[idx];
            int jj = idx / 144, c = idx % 144;
            *(float4*)&kpt[jj * 148 + c] = v;
        }
    }
    for (int idx = t; idx < CZ * NH; idx += 192) {   // Wb transposed
        int c = idx / NH, h = idx % NH;
        wbt[h * 132 + c] = Wb[idx];
    }
    qi[t] = ws[OFF_Q + i * 192 + t];
    if (t < 144) qpi[t] = ws[OFF_QPTS + i * 144 + t];
    if (t < NH) { hws[t] = log1pf(expf(hweights[t])) * 0.13608276348795434f; bbs[t] = bb[t]; }
    if (t < 16) mj[t] = mask[jt * 16 + t];
    if (t == 0) mi_s = mask[i];
    __syncthreads();

    const int jj = t / NH;   // 0..15
    const int h  = t % NH;

    float bsum = bbs[h];
    #pragma unroll 8
    for (int c = 0; c < CZ; c += 4) {
        float4 zv = *(const float4*)&zt[jj * 132 + c];
        float4 wv = *(const float4*)&wbt[h * 132 + c];
        bsum += zv.x * wv.x + zv.y * wv.y + zv.z * wv.z + zv.w * wv.w;
    }
    float qk = 0.f;
    #pragma unroll
    for (int c = 0; c < CH; c += 4) {
        float4 qv = *(const float4*)&qi[h * 16 + c];
        float4 kv = *(const float4*)&kt[jj * 200 + h * 16 + c];
        qk += qv.x * kv.x + qv.y * kv.y + qv.z * kv.z + qv.w * kv.w;
    }
    float d2 = 0.f;
    #pragma unroll
    for (int r = 0; r < 12; r += 4) {
        float4 qp = *(const float4*)&qpi[h * 12 + r];
        float4 kp = *(const float4*)&kpt[jj * 148 + h * 12 + r];
        float e0 = qp.x - kp.x, e1 = qp.y - kp.y, e2 = qp.z - kp.z, e3 = qp.w - kp.w;
        d2 += e0 * e0 + e1 * e1 + e2 * e2 + e3 * e3;
    }
    float sm = 100000.0f * (mi_s * mj[jj] - 1.0f);
    float logit = qk * 0.14433756729740643f + 0.5773502691896258f * bsum
                - 0.5f * hws[h] * d2 + sm;
    ws[OFF_A + ((size_t)i * NH + h) * N + jt * 16 + jj] = logit;
}

// ---------------- kernel 4: softmax, one (i,h) row per 64-thread block ----------------
__global__ __launch_bounds__(64) void softmax_kernel(float* __restrict__ ws)
{
    float* row = ws + OFF_A + (size_t)blockIdx.x * N;
    const int lane = threadIdx.x;
    float4 v0 = *(const float4*)&row[lane * 4];
    float4 v1 = *(const float4*)&row[256 + lane * 4];
    float m = fmaxf(fmaxf(fmaxf(v0.x, v0.y), fmaxf(v0.z, v0.w)),
                    fmaxf(fmaxf(v1.x, v1.y), fmaxf(v1.z, v1.w)));
    #pragma unroll
    for (int o = 32; o > 0; o >>= 1) m = fmaxf(m, __shfl_xor(m, o));
    v0.x = __expf(v0.x - m); v0.y = __expf(v0.y - m);
    v0.z = __expf(v0.z - m); v0.w = __expf(v0.w - m);
    v1.x = __expf(v1.x - m); v1.y = __expf(v1.y - m);
    v1.z = __expf(v1.z - m); v1.w = __expf(v1.w - m);
    float ssum = v0.x + v0.y + v0.z + v0.w + v1.x + v1.y + v1.z + v1.w;
    #pragma unroll
    for (int o = 32; o > 0; o >>= 1) ssum += __shfl_xor(ssum, o);
    float inv = 1.0f / ssum;
    v0.x *= inv; v0.y *= inv; v0.z *= inv; v0.w *= inv;
    v1.x *= inv; v1.y *= inv; v1.z *= inv; v1.w *= inv;
    *(float4*)&row[lane * 4] = v0;
    *(float4*)&row[256 + lane * 4] = v1;
}

// ---------------- kernel 5: o / o_pt / o_pair on disjoint wave groups ----------------
__global__ __launch_bounds__(832) void finish_kernel(
    const float* __restrict__ z, const float* __restrict__ t_trans,
    const float* __restrict__ t_rots, const float* __restrict__ ws_c,
    float* __restrict__ ws)
{
    const int i = blockIdx.x;
    const int t = threadIdx.x;
    __shared__ float a_s[12 * 520];

    {
        const float* src = ws_c + OFF_A + (size_t)i * (NH * N);
        for (int idx = t * 4; idx < NH * N; idx += 832 * 4) {
            float4 v = *(const float4*)&src[idx];
            int h = idx >> 9, j = idx & 511;
            *(float4*)&a_s[h * 520 + j] = v;
        }
    }
    __syncthreads();

    float* cat = ws + OFF_CAT + (size_t)i * 2112;

    if (t < 512) {          // o_pair: waves 0-7, thread = (head-group, channel)
        const int c = t & 127, hg = t >> 7;
        const float* zrow = z + (size_t)i * N * CZ + c;
        const float* a0 = a_s + (hg + 0) * 520;
        const float* a1 = a_s + (hg + 4) * 520;
        const float* a2 = a_s + (hg + 8) * 520;
        float acc0 = 0.f, acc1 = 0.f, acc2 = 0.f;
        #pragma unroll 8
        for (int j = 0; j < N; j++) {
            float zv = zrow[(size_t)j * CZ];
            acc0 += a0[j] * zv; acc1 += a1[j] * zv; acc2 += a2[j] * zv;
        }
        cat[576 + (hg + 0) * CZ + c] = acc0;
        cat[576 + (hg + 4) * CZ + c] = acc1;
        cat[576 + (hg + 8) * CZ + c] = acc2;
    } else if (t < 704) {   // o: waves 8-10 (192 threads)
        const int u = t - 512, h = u >> 4, cc = u & 15;
        const float* vcol = ws_c + OFF_V + h * 16 + cc;
        const float* ah = a_s + h * 520;
        float acc = 0.f;
        #pragma unroll 8
        for (int j = 0; j < N; j++)
            acc += ah[j] * vcol[j * 192];
        cat[h * 16 + cc] = acc;
    } else if (t < 800) {   // o_pt: 96 threads
        const int u = t - 704, h = u >> 3, p = u & 7;
        const float* vp = ws_c + OFF_VPTS + (h * PV + p) * 3;
        const float* ah = a_s + h * 520;
        float g0 = 0.f, g1 = 0.f, g2 = 0.f;
        #pragma unroll 4
        for (int j = 0; j < N; j++) {
            float av = ah[j];
            const float* vpj = vp + j * (NH * PV * 3);
            g0 += av * vpj[0]; g1 += av * vpj[1]; g2 += av * vpj[2];
        }
        float R[9], ti[3];
        #pragma unroll
        for (int x = 0; x < 9; x++) R[x] = t_rots[i * 9 + x];
        #pragma unroll
        for (int x = 0; x < 3; x++) ti[x] = t_trans[i * 3 + x];
        g0 -= ti[0]; g1 -= ti[1]; g2 -= ti[2];
        float l0 = R[0] * g0 + R[3] * g1 + R[6] * g2;
        float l1 = R[1] * g0 + R[4] * g1 + R[7] * g2;
        float l2 = R[2] * g0 + R[5] * g1 + R[8] * g2;
        float nrm = sqrtf(l0 * l0 + l1 * l1 + l2 * l2 + 1e-8f);
        int e = h * PV + p;
        cat[192 + e] = l0;
        cat[288 + e] = l1;
        cat[384 + e] = l2;
        cat[480 + e] = nrm;
    }
}

// ---------------- kernel 6a: init out with bias ----------------
__global__ __launch_bounds__(384) void init_out_kernel(
    const float* __restrict__ bout, float* __restrict__ out)
{
    out[(size_t)blockIdx.x * 384 + threadIdx.x] = bout[threadIdx.x];
}

// ---------------- kernel 6b: out += cat @ Wout (k-split, atomic) ----------------
__global__ __launch_bounds__(384) void out_kernel(
    const float* __restrict__ Wout, const float* __restrict__ ws,
    float* __restrict__ out)
{
    const int rt = blockIdx.x;   // 0..31: 16-row tile
    const int kc = blockIdx.y;   // 0..7:  264-k chunk
    const int t = threadIdx.x;
    __shared__ float ct[16 * 264];  // 16.5 KB
    for (int idx = t * 4; idx < 16 * 264; idx += 384 * 4) {
        int rr = idx / 264, kk = idx % 264;
        *(float4*)&ct[idx] =
            *(const float4*)&ws[OFF_CAT + (size_t)(rt * 16 + rr) * 2112 + kc * 264 + kk];
    }
    __syncthreads();
    const int cq = t % 96, rg = t / 96;
    const int c0 = cq * 4;
    float acc[4][4] = {};
    const float* Wp = Wout + (size_t)kc * 264 * 384 + c0;
    for (int kk = 0; kk < 264; kk++) {
        float4 w = *(const float4*)&Wp[(size_t)kk * 384];
        #pragma unroll
        for (int r = 0; r < 4; r++) {
            float sv = ct[(rg * 4 + r) * 264 + kk];
            acc[r][0] += sv * w.x; acc[r][1] += sv * w.y;
            acc[r][2] += sv * w.z; acc[r][3] += sv * w.w;
        }
    }
    #pragma unroll
    for (int r = 0; r < 4; r++) {
        float* op = out + (size_t)(rt * 16 + rg * 4 + r) * 384 + c0;
        atomicAdd(&op[0], acc[r][0]);
        atomicAdd(&op[1], acc[r][1]);
        atomicAdd(&op[2], acc[r][2]);
        atomicAdd(&op[3], acc[r][3]);
    }
}

extern "C" void kernel_launch(void* const* d_in, const int* in_sizes, int n_in,
                              void* d_out, int out_size, void* d_ws, size_t ws_size,
                              hipStream_t stream) {
    const float* s       = (const float*)d_in[0];
    const float* z       = (const float*)d_in[1];
    const float* t_trans = (const float*)d_in[2];
    const float* t_rots  = (const float*)d_in[3];
    const float* mask    = (const float*)d_in[4];
    const float* Wq      = (const float*)d_in[5];
    const float* bq      = (const float*)d_in[6];
    const float* Wkv     = (const float*)d_in[7];
    const float* bkv     = (const float*)d_in[8];
    const float* Wqp     = (const float*)d_in[9];
    const float* bqp     = (const float*)d_in[10];
    const float* Wkvp    = (const float*)d_in[11];
    const float* bkvp    = (const float*)d_in[12];
    const float* Wb      = (const float*)d_in[13];
    const float* bb      = (const float*)d_in[14];
    const float* hweights= (const float*)d_in[15];
    const float* Wout    = (const float*)d_in[16];
    const float* bout    = (const float*)d_in[17];
    float* ws  = (float*)d_ws;
    float* out = (float*)d_out;

    init_out_kernel<<<512, 384, 0, stream>>>(bout, out);
    proj_kernel<<<dim3(32, 9), 128, 0, stream>>>(s, Wq, bq, Wkv, bkv, Wqp, bqp, Wkvp, bkvp, ws);
    point_kernel<<<512, 192, 0, stream>>>(t_trans, t_rots, ws);
    logit_kernel<<<dim3(32, 512), 192, 0, stream>>>(z, Wb, bb, mask, hweights, ws);
    softmax_kernel<<<6144, 64, 0, stream>>>(ws);
    finish_kernel<<<512, 832, 0, stream>>>(z, t_trans, t_rots, ws, ws);
    out_kernel<<<dim3(32, 8), 384, 0, stream>>>(Wout, ws, out);
}

// Round 3
// 425.364 us; speedup vs baseline: 1.5585x; 1.1517x over previous
//
#include <hip/hip_runtime.h>
#include <math.h>

#define N 512
#define CS 384
#define CZ 128
#define CH 16
#define NH 12
#define PQ 4
#define PV 8

// workspace layout (float offsets)
#define OFF_Q     0          // 512*192
#define OFF_K     98304      // 512*192
#define OFF_V     196608     // 512*192
#define OFF_QRAW  294912     // 512*144
#define OFF_KVRAW 368640     // 512*432
#define OFF_QPTS  589824     // 512*144
#define OFF_KPTS  663552     // 512*144
#define OFF_VPTS  737280     // 512*288
#define OFF_A     884736     // 512*12*512 = 3145728  (A0 logits, then probs in place)
#define OFF_CAT   4030464    // 512*2112
// end = 5111808 floats

// ---------------- kernel 1: fused projections, 16-row register tile ----------------
__global__ __launch_bounds__(128) void proj_kernel(
    const float* __restrict__ s,
    const float* __restrict__ Wq,  const float* __restrict__ bq,
    const float* __restrict__ Wkv, const float* __restrict__ bkv,
    const float* __restrict__ Wqp, const float* __restrict__ bqp,
    const float* __restrict__ Wkvp,const float* __restrict__ bkvp,
    float* __restrict__ ws)
{
    __shared__ float st[16 * CS];   // 24 KB
    const int n0 = blockIdx.x * 16;
    for (int idx = threadIdx.x * 4; idx < 16 * CS; idx += 128 * 4)
        *(float4*)&st[idx] = *(const float4*)&s[n0 * CS + idx];
    __syncthreads();

    const int tc = threadIdx.x & 31;
    const int tr = threadIdx.x >> 5;
    const int u0 = blockIdx.y * 128 + tc * 4;
    const int r0 = tr * 4;

    const float* W; const float* bptr; int ncol, lc0;
    if (u0 < 192)      { W = Wq;   bptr = bq;   ncol = 192; lc0 = u0; }
    else if (u0 < 576) { W = Wkv;  bptr = bkv;  ncol = 384; lc0 = u0 - 192; }
    else if (u0 < 720) { W = Wqp;  bptr = bqp;  ncol = 144; lc0 = u0 - 576; }
    else               { W = Wkvp; bptr = bkvp; ncol = 432; lc0 = u0 - 720; }

    float acc[4][4];
    #pragma unroll
    for (int r = 0; r < 4; r++)
        #pragma unroll
        for (int c = 0; c < 4; c++) acc[r][c] = 0.f;

    for (int k = 0; k < CS; k += 4) {
        float4 w0 = *(const float4*)&W[(k + 0) * ncol + lc0];
        float4 w1 = *(const float4*)&W[(k + 1) * ncol + lc0];
        float4 w2 = *(const float4*)&W[(k + 2) * ncol + lc0];
        float4 w3 = *(const float4*)&W[(k + 3) * ncol + lc0];
        #pragma unroll
        for (int r = 0; r < 4; r++) {
            float4 sv = *(const float4*)&st[(r0 + r) * CS + k];
            acc[r][0] += sv.x * w0.x + sv.y * w1.x + sv.z * w2.x + sv.w * w3.x;
            acc[r][1] += sv.x * w0.y + sv.y * w1.y + sv.z * w2.y + sv.w * w3.y;
            acc[r][2] += sv.x * w0.z + sv.y * w1.z + sv.z * w2.z + sv.w * w3.z;
            acc[r][3] += sv.x * w0.w + sv.y * w1.w + sv.z * w2.w + sv.w * w3.w;
        }
    }

    #pragma unroll
    for (int c = 0; c < 4; c++) {
        const int u = u0 + c;
        const float bias = bptr[lc0 + c];
        #pragma unroll
        for (int r = 0; r < 4; r++) {
            const int n = n0 + r0 + r;
            int oidx;
            if (u < 192) oidx = OFF_Q + n * 192 + u;
            else if (u < 576) {
                int lc = u - 192, h = lc >> 5, w = lc & 31;
                oidx = (w < 16) ? OFF_K + n * 192 + h * 16 + w
                                : OFF_V + n * 192 + h * 16 + (w - 16);
            } else if (u < 720) oidx = OFF_QRAW + n * 144 + (u - 576);
            else                oidx = OFF_KVRAW + n * 432 + (u - 720);
            ws[oidx] = acc[r][c] + bias;
        }
    }
}

// ---------------- kernel 2: rigid transform of point projections ----------------
__global__ __launch_bounds__(192) void point_kernel(
    const float* __restrict__ t_trans, const float* __restrict__ t_rots,
    float* __restrict__ ws)
{
    const int n = blockIdx.x;
    const int t = threadIdx.x;
    __shared__ float R[9], tr[3];
    if (t < 9) R[t] = t_rots[n * 9 + t];
    if (t < 3) tr[t] = t_trans[n * 3 + t];
    __syncthreads();

    float x0, x1, x2;
    int base;
    if (t < 48) {
        int idx = t;
        x0 = ws[OFF_QRAW + n * 144 + 0 * 48 + idx];
        x1 = ws[OFF_QRAW + n * 144 + 1 * 48 + idx];
        x2 = ws[OFF_QRAW + n * 144 + 2 * 48 + idx];
        int h = idx >> 2, p = idx & 3;
        base = OFF_QPTS + ((n * NH + h) * PQ + p) * 3;
    } else {
        int idx = t - 48;
        x0 = ws[OFF_KVRAW + n * 432 + 0 * 144 + idx];
        x1 = ws[OFF_KVRAW + n * 432 + 1 * 144 + idx];
        x2 = ws[OFF_KVRAW + n * 432 + 2 * 144 + idx];
        int h = idx / 12, p = idx % 12;
        if (p < PQ) base = OFF_KPTS + ((n * NH + h) * PQ + p) * 3;
        else        base = OFF_VPTS + ((n * NH + h) * PV + (p - PQ)) * 3;
    }
    ws[base + 0] = R[0] * x0 + R[1] * x1 + R[2] * x2 + tr[0];
    ws[base + 1] = R[3] * x0 + R[4] * x1 + R[5] * x2 + tr[1];
    ws[base + 2] = R[6] * x0 + R[7] * x1 + R[8] * x2 + tr[2];
}

// ---------------- kernel 3: A0 = cqk*qk - 0.5*hw*d2 + mask (z-independent logits) ----------------
// grid (j-tile 32, i-tile 32), 192 threads = 16 jj x 12 h; each thread loops 16 i's
// k/kpt fragments live in registers (loaded once); q/qpt read per-i as b128 from LDS.
__global__ __launch_bounds__(192) void logitA_kernel(
    const float* __restrict__ mask, const float* __restrict__ hweights,
    float* __restrict__ ws)
{
    const int j0 = blockIdx.x * 16;
    const int i0 = blockIdx.y * 16;
    const int t = threadIdx.x;

    __shared__ float qt[16 * 200];
    __shared__ float kt[16 * 200];
    __shared__ float qpt[16 * 148];
    __shared__ float kpt[16 * 148];
    __shared__ float mi[16], mj[16];

    {
        const float* src = ws + OFF_Q + i0 * 192;
        for (int idx = t * 4; idx < 3072; idx += 768) {
            float4 v = *(const float4*)&src[idx];
            *(float4*)&qt[(idx / 192) * 200 + idx % 192] = v;
        }
    }
    {
        const float* src = ws + OFF_K + j0 * 192;
        for (int idx = t * 4; idx < 3072; idx += 768) {
            float4 v = *(const float4*)&src[idx];
            *(float4*)&kt[(idx / 192) * 200 + idx % 192] = v;
        }
    }
    {
        const float* src = ws + OFF_QPTS + i0 * 144;
        for (int idx = t * 4; idx < 2304; idx += 768) {
            float4 v = *(const float4*)&src[idx];
            *(float4*)&qpt[(idx / 144) * 148 + idx % 144] = v;
        }
    }
    {
        const float* src = ws + OFF_KPTS + j0 * 144;
        for (int idx = t * 4; idx < 2304; idx += 768) {
            float4 v = *(const float4*)&src[idx];
            *(float4*)&kpt[(idx / 144) * 148 + idx % 144] = v;
        }
    }
    if (t < 16) { mi[t] = mask[i0 + t]; mj[t] = mask[j0 + t]; }
    __syncthreads();

    const int jj = t & 15;
    const int h = t >> 4;
    const float hw = log1pf(expf(hweights[h])) * 0.13608276348795434f;
    const float cqk = 0.14433756729740643f;

    float4 kr0 = *(const float4*)&kt[jj * 200 + h * 16 + 0];
    float4 kr1 = *(const float4*)&kt[jj * 200 + h * 16 + 4];
    float4 kr2 = *(const float4*)&kt[jj * 200 + h * 16 + 8];
    float4 kr3 = *(const float4*)&kt[jj * 200 + h * 16 + 12];
    float4 kp0 = *(const float4*)&kpt[jj * 148 + h * 12 + 0];
    float4 kp1 = *(const float4*)&kpt[jj * 148 + h * 12 + 4];
    float4 kp2 = *(const float4*)&kpt[jj * 148 + h * 12 + 8];
    const float mjv = mj[jj];

    for (int ii = 0; ii < 16; ii++) {
        float4 q0 = *(const float4*)&qt[ii * 200 + h * 16 + 0];
        float4 q1 = *(const float4*)&qt[ii * 200 + h * 16 + 4];
        float4 q2 = *(const float4*)&qt[ii * 200 + h * 16 + 8];
        float4 q3 = *(const float4*)&qt[ii * 200 + h * 16 + 12];
        float qk = q0.x * kr0.x + q0.y * kr0.y + q0.z * kr0.z + q0.w * kr0.w
                 + q1.x * kr1.x + q1.y * kr1.y + q1.z * kr1.z + q1.w * kr1.w
                 + q2.x * kr2.x + q2.y * kr2.y + q2.z * kr2.z + q2.w * kr2.w
                 + q3.x * kr3.x + q3.y * kr3.y + q3.z * kr3.z + q3.w * kr3.w;
        float4 p0 = *(const float4*)&qpt[ii * 148 + h * 12 + 0];
        float4 p1 = *(const float4*)&qpt[ii * 148 + h * 12 + 4];
        float4 p2 = *(const float4*)&qpt[ii * 148 + h * 12 + 8];
        float e, d2 = 0.f;
        e = p0.x - kp0.x; d2 += e * e;  e = p0.y - kp0.y; d2 += e * e;
        e = p0.z - kp0.z; d2 += e * e;  e = p0.w - kp0.w; d2 += e * e;
        e = p1.x - kp1.x; d2 += e * e;  e = p1.y - kp1.y; d2 += e * e;
        e = p1.z - kp1.z; d2 += e * e;  e = p1.w - kp1.w; d2 += e * e;
        e = p2.x - kp2.x; d2 += e * e;  e = p2.y - kp2.y; d2 += e * e;
        e = p2.z - kp2.z; d2 += e * e;  e = p2.w - kp2.w; d2 += e * e;
        float sm = 100000.0f * (mi[ii] * mjv - 1.0f);
        ws[OFF_A + ((size_t)(i0 + ii) * NH + h) * N + j0 + jj] =
            qk * cqk - 0.5f * hw * d2 + sm;
    }
}

// ---------------- kernel 4: b = z@Wb fused with +A0 and softmax (one block per i) ----------------
// 512 threads: jj = t&127 (j within 128-tile), hg = t>>7 (3 heads each). 4 j-tiles.
__global__ __launch_bounds__(512) void bsoft_kernel(
    const float* __restrict__ z, const float* __restrict__ Wb,
    const float* __restrict__ bb, float* __restrict__ ws)
{
    const int i = blockIdx.x;
    const int t = threadIdx.x;
    __shared__ float zt[128 * 132];   // 67.6 KB, stride 132 -> conflict-free b128 rows
    __shared__ float wbt[12 * 132];   // Wb transposed [h][c]
    __shared__ float wred[8][4];      // per-wave softmax partials

    for (int idx = t; idx < CZ * NH; idx += 512) {
        int c = idx / NH, h = idx % NH;
        wbt[h * 132 + c] = Wb[idx];
    }

    const int jj = t & 127;
    const int hg = t >> 7;      // 0..3
    const int h0 = hg * 3;
    const float bb0 = bb[h0], bb1 = bb[h0 + 1], bb2 = bb[h0 + 2];
    const float cb = 0.5773502691896258f;

    float lg[3][4];

    for (int T = 0; T < 4; T++) {
        __syncthreads();
        const float* zsrc = z + ((size_t)i * N + T * 128) * CZ;
        for (int idx = t * 4; idx < 16384; idx += 2048) {
            float4 v = *(const float4*)&zsrc[idx];
            *(float4*)&zt[(idx >> 7) * 132 + (idx & 127)] = v;
        }
        __syncthreads();

        float a0 = bb0, a1 = bb1, a2 = bb2;
        const float* zr = &zt[jj * 132];
        const float* w0 = &wbt[(h0 + 0) * 132];
        const float* w1 = &wbt[(h0 + 1) * 132];
        const float* w2 = &wbt[(h0 + 2) * 132];
        #pragma unroll
        for (int c = 0; c < CZ; c += 4) {
            float4 zq = *(const float4*)&zr[c];
            float4 q0 = *(const float4*)&w0[c];
            float4 q1 = *(const float4*)&w1[c];
            float4 q2 = *(const float4*)&w2[c];
            a0 += zq.x * q0.x + zq.y * q0.y + zq.z * q0.z + zq.w * q0.w;
            a1 += zq.x * q1.x + zq.y * q1.y + zq.z * q1.z + zq.w * q1.w;
            a2 += zq.x * q2.x + zq.y * q2.y + zq.z * q2.z + zq.w * q2.w;
        }
        const float* arow = ws + OFF_A + (size_t)i * NH * N + T * 128 + jj;
        lg[0][T] = arow[(size_t)(h0 + 0) * N] + cb * a0;
        lg[1][T] = arow[(size_t)(h0 + 1) * N] + cb * a1;
        lg[2][T] = arow[(size_t)(h0 + 2) * N] + cb * a2;
    }

    // softmax over j (512 values per (i,h), spread across 128 threads x 4 T)
    const int wv = t >> 6;
    float mx[3], sm[3];
    #pragma unroll
    for (int r = 0; r < 3; r++) {
        float m = fmaxf(fmaxf(lg[r][0], lg[r][1]), fmaxf(lg[r][2], lg[r][3]));
        #pragma unroll
        for (int o = 32; o > 0; o >>= 1) m = fmaxf(m, __shfl_xor(m, o));
        mx[r] = m;
    }
    if ((t & 63) == 0) {
        wred[wv][0] = mx[0]; wred[wv][1] = mx[1]; wred[wv][2] = mx[2];
    }
    __syncthreads();
    #pragma unroll
    for (int r = 0; r < 3; r++)
        mx[r] = fmaxf(wred[hg * 2][r], wred[hg * 2 + 1][r]);
    __syncthreads();   // protect wred reuse
    #pragma unroll
    for (int r = 0; r < 3; r++) {
        float s = 0.f;
        #pragma unroll
        for (int T = 0; T < 4; T++) { lg[r][T] = __expf(lg[r][T] - mx[r]); s += lg[r][T]; }
        #pragma unroll
        for (int o = 32; o > 0; o >>= 1) s += __shfl_xor(s, o);
        sm[r] = s;
    }
    if ((t & 63) == 0) {
        wred[wv][0] = sm[0]; wred[wv][1] = sm[1]; wred[wv][2] = sm[2];
    }
    __syncthreads();
    #pragma unroll
    for (int r = 0; r < 3; r++) {
        float inv = 1.0f / (wred[hg * 2][r] + wred[hg * 2 + 1][r]);
        float* prow = ws + OFF_A + ((size_t)i * NH + h0 + r) * N + jj;
        #pragma unroll
        for (int T = 0; T < 4; T++)
            prow[T * 128] = lg[r][T] * inv;
    }
}

// ---------------- kernel 5: o / o_pt / o_pair on disjoint wave groups ----------------
__global__ __launch_bounds__(832) void finish_kernel(
    const float* __restrict__ z, const float* __restrict__ t_trans,
    const float* __restrict__ t_rots, const float* __restrict__ ws_c,
    float* __restrict__ ws)
{
    const int i = blockIdx.x;
    const int t = threadIdx.x;
    __shared__ float a_s[12 * 520];

    {
        const float* src = ws_c + OFF_A + (size_t)i * (NH * N);
        for (int idx = t * 4; idx < NH * N; idx += 832 * 4) {
            float4 v = *(const float4*)&src[idx];
            int h = idx >> 9, j = idx & 511;
            *(float4*)&a_s[h * 520 + j] = v;
        }
    }
    __syncthreads();

    float* cat = ws + OFF_CAT + (size_t)i * 2112;

    if (t < 512) {          // o_pair
        const int c = t & 127, hg = t >> 7;
        const float* zrow = z + (size_t)i * N * CZ + c;
        const float* a0 = a_s + (hg + 0) * 520;
        const float* a1 = a_s + (hg + 4) * 520;
        const float* a2 = a_s + (hg + 8) * 520;
        float acc0 = 0.f, acc1 = 0.f, acc2 = 0.f;
        #pragma unroll 8
        for (int j = 0; j < N; j++) {
            float zv = zrow[(size_t)j * CZ];
            acc0 += a0[j] * zv; acc1 += a1[j] * zv; acc2 += a2[j] * zv;
        }
        cat[576 + (hg + 0) * CZ + c] = acc0;
        cat[576 + (hg + 4) * CZ + c] = acc1;
        cat[576 + (hg + 8) * CZ + c] = acc2;
    } else if (t < 704) {   // o
        const int u = t - 512, h = u >> 4, cc = u & 15;
        const float* vcol = ws_c + OFF_V + h * 16 + cc;
        const float* ah = a_s + h * 520;
        float acc = 0.f;
        #pragma unroll 8
        for (int j = 0; j < N; j++)
            acc += ah[j] * vcol[j * 192];
        cat[h * 16 + cc] = acc;
    } else if (t < 800) {   // o_pt
        const int u = t - 704, h = u >> 3, p = u & 7;
        const float* vp = ws_c + OFF_VPTS + (h * PV + p) * 3;
        const float* ah = a_s + h * 520;
        float g0 = 0.f, g1 = 0.f, g2 = 0.f;
        #pragma unroll 4
        for (int j = 0; j < N; j++) {
            float av = ah[j];
            const float* vpj = vp + j * (NH * PV * 3);
            g0 += av * vpj[0]; g1 += av * vpj[1]; g2 += av * vpj[2];
        }
        float R[9], ti[3];
        #pragma unroll
        for (int x = 0; x < 9; x++) R[x] = t_rots[i * 9 + x];
        #pragma unroll
        for (int x = 0; x < 3; x++) ti[x] = t_trans[i * 3 + x];
        g0 -= ti[0]; g1 -= ti[1]; g2 -= ti[2];
        float l0 = R[0] * g0 + R[3] * g1 + R[6] * g2;
        float l1 = R[1] * g0 + R[4] * g1 + R[7] * g2;
        float l2 = R[2] * g0 + R[5] * g1 + R[8] * g2;
        float nrm = sqrtf(l0 * l0 + l1 * l1 + l2 * l2 + 1e-8f);
        int e = h * PV + p;
        cat[192 + e] = l0;
        cat[288 + e] = l1;
        cat[384 + e] = l2;
        cat[480 + e] = nrm;
    }
}

// ---------------- kernel 6a: init out with bias ----------------
__global__ __launch_bounds__(384) void init_out_kernel(
    const float* __restrict__ bout, float* __restrict__ out)
{
    out[(size_t)blockIdx.x * 384 + threadIdx.x] = bout[threadIdx.x];
}

// ---------------- kernel 6b: out += cat @ Wout (k-split, atomic) ----------------
__global__ __launch_bounds__(384) void out_kernel(
    const float* __restrict__ Wout, const float* __restrict__ ws,
    float* __restrict__ out)
{
    const int rt = blockIdx.x;
    const int kc = blockIdx.y;
    const int t = threadIdx.x;
    __shared__ float ct[16 * 264];
    for (int idx = t * 4; idx < 16 * 264; idx += 384 * 4) {
        int rr = idx / 264, kk = idx % 264;
        *(float4*)&ct[idx] =
            *(const float4*)&ws[OFF_CAT + (size_t)(rt * 16 + rr) * 2112 + kc * 264 + kk];
    }
    __syncthreads();
    const int cq = t % 96, rg = t / 96;
    const int c0 = cq * 4;
    float acc[4][4] = {};
    const float* Wp = Wout + (size_t)kc * 264 * 384 + c0;
    for (int kk = 0; kk < 264; kk++) {
        float4 w = *(const float4*)&Wp[(size_t)kk * 384];
        #pragma unroll
        for (int r = 0; r < 4; r++) {
            float sv = ct[(rg * 4 + r) * 264 + kk];
            acc[r][0] += sv * w.x; acc[r][1] += sv * w.y;
            acc[r][2] += sv * w.z; acc[r][3] += sv * w.w;
        }
    }
    #pragma unroll
    for (int r = 0; r < 4; r++) {
        float* op = out + (size_t)(rt * 16 + rg * 4 + r) * 384 + c0;
        atomicAdd(&op[0], acc[r][0]);
        atomicAdd(&op[1], acc[r][1]);
        atomicAdd(&op[2], acc[r][2]);
        atomicAdd(&op[3], acc[r][3]);
    }
}

extern "C" void kernel_launch(void* const* d_in, const int* in_sizes, int n_in,
                              void* d_out, int out_size, void* d_ws, size_t ws_size,
                              hipStream_t stream) {
    const float* s       = (const float*)d_in[0];
    const float* z       = (const float*)d_in[1];
    const float* t_trans = (const float*)d_in[2];
    const float* t_rots  = (const float*)d_in[3];
    const float* mask    = (const float*)d_in[4];
    const float* Wq      = (const float*)d_in[5];
    const float* bq      = (const float*)d_in[6];
    const float* Wkv     = (const float*)d_in[7];
    const float* bkv     = (const float*)d_in[8];
    const float* Wqp     = (const float*)d_in[9];
    const float* bqp     = (const float*)d_in[10];
    const float* Wkvp    = (const float*)d_in[11];
    const float* bkvp    = (const float*)d_in[12];
    const float* Wb      = (const float*)d_in[13];
    const float* bb      = (const float*)d_in[14];
    const float* hweights= (const float*)d_in[15];
    const float* Wout    = (const float*)d_in[16];
    const float* bout    = (const float*)d_in[17];
    float* ws  = (float*)d_ws;
    float* out = (float*)d_out;

    init_out_kernel<<<512, 384, 0, stream>>>(bout, out);
    proj_kernel<<<dim3(32, 9), 128, 0, stream>>>(s, Wq, bq, Wkv, bkv, Wqp, bqp, Wkvp, bkvp, ws);
    point_kernel<<<512, 192, 0, stream>>>(t_trans, t_rots, ws);
    logitA_kernel<<<dim3(32, 32), 192, 0, stream>>>(mask, hweights, ws);
    bsoft_kernel<<<512, 512, 0, stream>>>(z, Wb, bb, ws);
    finish_kernel<<<512, 832, 0, stream>>>(z, t_trans, t_rots, ws, ws);
    out_kernel<<<dim3(32, 8), 384, 0, stream>>>(Wout, ws, out);
}